// Round 5
// baseline (888.492 us; speedup 1.0000x reference)
//
#include <hip/hip_runtime.h>

// TT-LSTM: B=64, T=1024, D=H=256, F=16, R=16, NG=4.
// ws layout (floats):
//   A1ihT [64][256]  @ 0       ([g*16+s][m*16+n], composed g0*g1 for ih)
//   A1hT  [64][256]  @ 16384   (same for hh)
//   C2ih  [64][256]  @ 32768   ([g*16+s][o*16+p], composed g2*g3 for ih)
//   C2h   [64][256]  @ 49152
//   biasS [4][256]   @ 65536   (ih_bias + hh_bias)
//   T2ih  [65536][64]@ 66560   (first-stage ih contraction for all rows)

#define WS_A1I 0
#define WS_A1H 16384
#define WS_C2I 32768
#define WS_C2H 49152
#define WS_BIAS 65536
#define WS_T2 66560

typedef float v2f __attribute__((ext_vector_type(2)));

// Packed fp32 FMA: 2 FMAs/instruction.
__device__ __forceinline__ v2f pk_fma(v2f a, v2f b, v2f c) {
    v2f d;
    asm("v_pk_fma_f32 %0, %1, %2, %3" : "=v"(d) : "v"(a), "v"(b), "v"(c));
    return d;
}

// Barrier draining LDS only (lgkmcnt), NOT global loads/stores (vmcnt).
__device__ __forceinline__ void bar_lds() {
    asm volatile("s_waitcnt lgkmcnt(0)\n\ts_barrier" ::: "memory");
}

// DPP helpers: cross-lane at VALU rate (no DS pipe).
// row_shr:n = 0x110|n ; quad_perm(k,k,k,k) = k*0x55. bound_ctrl=1 -> 0 fill.
template <int CTRL>
__device__ __forceinline__ float dpp_add(float v) {
    int s = __builtin_amdgcn_update_dpp(0, __float_as_int(v), CTRL, 0xF, 0xF, true);
    return v + __int_as_float(s);
}
template <int CTRL>
__device__ __forceinline__ float dpp_bcast(float v) {
    int s = __builtin_amdgcn_update_dpp(0, __float_as_int(v), CTRL, 0xF, 0xF, true);
    return __int_as_float(s);
}

// ---------------- K0: compose TT cores ----------------
__global__ void k_compose(const float* __restrict__ g0i, const float* __restrict__ g1i,
                          const float* __restrict__ g2i, const float* __restrict__ g3i,
                          const float* __restrict__ bi,
                          const float* __restrict__ g0h, const float* __restrict__ g1h,
                          const float* __restrict__ g2h, const float* __restrict__ g3h,
                          const float* __restrict__ bh,
                          float* __restrict__ ws) {
    int id = blockIdx.x * 256 + threadIdx.x;
    if (id < 16384) {
        int g = id >> 12, s = (id >> 8) & 15, mn = id & 255;
        int m = mn >> 4, n = mn & 15;
        float aI = 0.f, aH = 0.f;
        for (int r = 0; r < 16; ++r) {
            aI += g0i[(g * 16 + m) * 16 + r] * g1i[((g * 16 + r) * 16 + n) * 16 + s];
            aH += g0h[(g * 16 + m) * 16 + r] * g1h[((g * 16 + r) * 16 + n) * 16 + s];
        }
        ws[WS_A1I + (g * 16 + s) * 256 + mn] = aI;
        ws[WS_A1H + (g * 16 + s) * 256 + mn] = aH;
    } else if (id < 32768) {
        int id2 = id - 16384;
        int g = id2 >> 12, s = (id2 >> 8) & 15, j = id2 & 255;
        int o = j >> 4, p = j & 15;
        float aI = 0.f, aH = 0.f;
        for (int t = 0; t < 16; ++t) {
            aI += g2i[((g * 16 + s) * 16 + o) * 16 + t] * g3i[(g * 16 + t) * 16 + p];
            aH += g2h[((g * 16 + s) * 16 + o) * 16 + t] * g3h[(g * 16 + t) * 16 + p];
        }
        ws[WS_C2I + (g * 16 + s) * 256 + j] = aI;
        ws[WS_C2H + (g * 16 + s) * 256 + j] = aH;
    } else if (id < 33792) {
        int id2 = id - 32768;
        ws[WS_BIAS + id2] = bi[id2] + bh[id2];
    }
}

// ---------------- K1: T2ih = X @ A1ih ----------------
// r5: async-stage split (T14). r1-r3 evidence: not DS-throughput bound
// (27us floor), not issue bound (9us floor), not occupancy (r2's 4blk/CU
// didn't help) -> the ~121us is global-staging latency serialized by the
// per-half barriers (load -> vmcnt0 -> ds_write -> bar -> compute exposes
// ~900cy HBM latency per half with nothing in flight during compute).
// Fix: issue half1's global loads into REGISTERS before computing half0;
// vmcnt+ds_write after the WAR barrier. Latency hides under ~4000cy of
// compute. Same LDS layout/swizzle as r1 (2-way reads, free).
__global__ __launch_bounds__(256, 2) void k_t2ih(const float* __restrict__ x,
                                                 const float* __restrict__ ws,
                                                 float* __restrict__ T2) {
    __shared__ __align__(16) float Xs[64 * 128];
    __shared__ __align__(16) float As[64 * 128];
    const int tid = threadIdx.x;
    const long r0 = (long)blockIdx.x * 64;
    const int ro = tid & 15;
    const int q  = tid >> 4;

    const float4* X4g = (const float4*)x;            // row stride 64 float4
    const float4* A4  = (const float4*)(ws + WS_A1I);
    float4* Xs4 = (float4*)Xs;                       // 32 float4 per row
    float4* As4 = (float4*)As;

    v2f acc2[4][4];
#pragma unroll
    for (int i = 0; i < 4; ++i)
#pragma unroll
        for (int j = 0; j < 4; ++j) acc2[i][j] = (v2f){0.f, 0.f};

    // staging geometry (same both halves)
    int swd[8], grx[8], gra[8];
#pragma unroll
    for (int k = 0; k < 8; ++k) {
        int idx = k * 256 + tid;                     // 0..2047
        int row = idx >> 5, c = idx & 31;
        swd[k] = (row << 5) | (c ^ ((row >> 2) & 15));
        grx[k] = (int)((r0 + row) * 64 + c);         // + half*32 later
        gra[k] = row * 64 + c;
    }

    float4 xb[8], ab[8];
    // prefetch half 0
#pragma unroll
    for (int k = 0; k < 8; ++k) { xb[k] = X4g[grx[k]]; ab[k] = A4[gra[k]]; }

    auto compute = [&]() {
#pragma unroll 4
        for (int mn4 = 0; mn4 < 32; ++mn4) {
            float4 a[4], xv[4];
#pragma unroll
            for (int j = 0; j < 4; ++j)
                a[j] = As4[((ro * 4 + j) << 5) | (mn4 ^ ro)];
#pragma unroll
            for (int i = 0; i < 4; ++i)
                xv[i] = Xs4[((q * 4 + i) << 5) | (mn4 ^ q)];
#pragma unroll
            for (int i = 0; i < 4; ++i)
#pragma unroll
                for (int j = 0; j < 4; ++j) {
                    acc2[i][j] = pk_fma((v2f){xv[i].x, xv[i].y},
                                        (v2f){a[j].x, a[j].y}, acc2[i][j]);
                    acc2[i][j] = pk_fma((v2f){xv[i].z, xv[i].w},
                                        (v2f){a[j].z, a[j].w}, acc2[i][j]);
                }
        }
    };

    // write half 0 (vmcnt inserted by compiler), then start half-1 loads
#pragma unroll
    for (int k = 0; k < 8; ++k) { Xs4[swd[k]] = xb[k]; As4[swd[k]] = ab[k]; }
    __syncthreads();
#pragma unroll
    for (int k = 0; k < 8; ++k) { xb[k] = X4g[grx[k] + 32]; ab[k] = A4[gra[k] + 32]; }

    compute();                                       // half 0; loads in flight
    __syncthreads();                                 // WAR
#pragma unroll
    for (int k = 0; k < 8; ++k) { Xs4[swd[k]] = xb[k]; As4[swd[k]] = ab[k]; }
    __syncthreads();
    compute();                                       // half 1

#pragma unroll
    for (int i = 0; i < 4; ++i)
#pragma unroll
        for (int j = 0; j < 4; ++j)
            T2[(r0 + q * 4 + i) * 64 + ro * 4 + j] = acc2[i][j].x + acc2[i][j].y;
}

// ---------------- K2: recurrent LSTM ----------------
// r5 = r4 (512 thr / 8 waves / 2 outputs per thread, 723us) + ti4-hoist:
// t2iS[t&1] was written at AB(t-1) behind barrier1(t-1) -> its reads are
// safe anywhere in AB(t). Hoist the 4 float4 READS into AB (registers);
// the ih FMAs STAY in CD as an independent chain that executes while the
// th4 reads are in flight -> removes one LDS-read latency (~120cy) from
// the post-barrier-1 serial path. (r2's regression moved the FMAs too,
// which emptied CD of latency-filler work - not repeated here.)
__global__ __launch_bounds__(512, 2) void k_lstm(const float* __restrict__ ws,
                                                 const float* __restrict__ T2,
                                                 float* __restrict__ out) {
    __shared__ __align__(16) float hS[256];
    __shared__ __align__(16) float t2hS[64];
    __shared__ __align__(16) float t2iS[2][64];

    const int tid  = threadIdx.x;
    const int w    = tid >> 6;                          // 0..7
    const int lane = tid & 63;
    const int b    = blockIdx.x;

    // ---- AB weights: rows u0 and u1 = u0+32 of A1h, cols sub*16..+15 ----
    const int uab = 4 * w + (lane >> 4);                // 0..31
    const int sub = lane & 15;
    v2f a1p0[8], a1p1[8];
    {
        const float4* A1h4 = (const float4*)(ws + WS_A1H);
#pragma unroll
        for (int kk = 0; kk < 4; ++kk) {
            float4 v0 = A1h4[uab * 64 + sub * 4 + kk];
            float4 v1 = A1h4[(uab + 32) * 64 + sub * 4 + kk];
            a1p0[2 * kk + 0] = (v2f){v0.x, v0.y};
            a1p0[2 * kk + 1] = (v2f){v0.z, v0.w};
            a1p1[2 * kk + 0] = (v2f){v1.x, v1.y};
            a1p1[2 * kk + 1] = (v2f){v1.z, v1.w};
        }
    }

    // ---- CD weights: g=lane&3, jj=lane>>2, j0=16w+jj, j1=j0+128 ----
    const int jj = lane >> 2;                           // 0..15
    const int g  = lane & 3;
    const int j0 = 16 * w + jj;                         // 0..127
    const int j1 = j0 + 128;                            // 128..255
    v2f c2hp0[8], c2ip0[8], c2hp1[8], c2ip1[8];
#pragma unroll
    for (int qq = 0; qq < 4; ++qq) {
#pragma unroll
        for (int hh = 0; hh < 2; ++hh) {
            int s0 = 16 * g + 4 * qq + 2 * hh;
            c2hp0[2 * qq + hh] = (v2f){ws[WS_C2H + (s0 + 0) * 256 + j0],
                                       ws[WS_C2H + (s0 + 1) * 256 + j0]};
            c2ip0[2 * qq + hh] = (v2f){ws[WS_C2I + (s0 + 0) * 256 + j0],
                                       ws[WS_C2I + (s0 + 1) * 256 + j0]};
            c2hp1[2 * qq + hh] = (v2f){ws[WS_C2H + (s0 + 0) * 256 + j1],
                                       ws[WS_C2H + (s0 + 1) * 256 + j1]};
            c2ip1[2 * qq + hh] = (v2f){ws[WS_C2I + (s0 + 0) * 256 + j1],
                                       ws[WS_C2I + (s0 + 1) * 256 + j1]};
        }
    }
    float bias0 = ws[WS_BIAS + g * 256 + j0];
    float bias1 = ws[WS_BIAS + g * 256 + j1];
    const float am = (g == 2) ? 2.0f : 1.0f;            // tanh vs sigmoid
    const float as = 1.442695040888963f * am;

#pragma unroll
    for (int i = 0; i < 8; ++i)
        asm volatile("" : "+v"(a1p0[i]), "+v"(a1p1[i]), "+v"(c2hp0[i]),
                         "+v"(c2ip0[i]), "+v"(c2hp1[i]), "+v"(c2ip1[i]));

    // transposed hS slots: h[j] at word 64*((j&15)>>2) + 4*(j>>4) + (j&3)
    const int hw0 = ((jj >> 2) << 6) + 4 * w + (jj & 3);
    const int hw1 = hw0 + 32;                           // j1: j>>4 = w+8

    float c0 = 0.f, c1 = 0.f, h0l = 0.f, h1l = 0.f;
    if (tid < 256) hS[tid] = 0.f;
    const float* T2b = T2 + (long)b * 1024 * 64;
    const float4* T2b4 = (const float4*)T2b;
    float4 preA = make_float4(0.f, 0.f, 0.f, 0.f);
    float4 preB = make_float4(0.f, 0.f, 0.f, 0.f);
    if (tid < 16) {
        ((float4*)t2iS[0])[tid] = T2b4[tid];
        preA = T2b4[16 + tid];                          // T2[t=1]
    }
    bar_lds();

    float* outB = out + (long)b * 1024 * 256;
    const float4* hS4 = (const float4*)hS;
    const float4* th4 = (const float4*)t2hS;

    auto body = [&](int t, float4& preW, float4& preL) {
        // ---- hoisted ti reads (t2iS[t&1] is 2 barriers old: safe) ----
        const float4* ti4 = (const float4*)t2iS[t & 1];
        float4 tiR[4];
#pragma unroll
        for (int qq = 0; qq < 4; ++qq) tiR[qq] = ti4[g * 4 + qq];

        // ---- AB (packed, 2 u-rows) ----
        v2f sA0 = (v2f){0.f, 0.f}, sB0 = (v2f){0.f, 0.f};
        v2f sA1 = (v2f){0.f, 0.f}, sB1 = (v2f){0.f, 0.f};
#pragma unroll
        for (int kk = 0; kk < 4; ++kk) {
            float4 hv = hS4[kk * 16 + sub];             // 2-way bcast, free
            v2f hxy = (v2f){hv.x, hv.y}, hzw = (v2f){hv.z, hv.w};
            sA0 = pk_fma(hxy, a1p0[2 * kk + 0], sA0);
            sB0 = pk_fma(hzw, a1p0[2 * kk + 1], sB0);
            sA1 = pk_fma(hxy, a1p1[2 * kk + 0], sA1);
            sB1 = pk_fma(hzw, a1p1[2 * kk + 1], sB1);
        }
        float tv0 = (sA0.x + sA0.y) + (sB0.x + sB0.y);
        float tv1 = (sA1.x + sA1.y) + (sB1.x + sB1.y);
        // stage next t2i + prefetch (independent; overlaps DPP chains)
        if ((tid < 16) && (t + 1 < 1024))
            ((float4*)t2iS[(t + 1) & 1])[tid] = preW;
        if ((tid < 16) && (t + 2 < 1024))
            preL = T2b4[(t + 2) * 16 + tid];
        // two interleaved DPP sums over the 16-lane row -> totals in sub==15
        tv0 = dpp_add<0x111>(tv0);  tv1 = dpp_add<0x111>(tv1);
        tv0 = dpp_add<0x112>(tv0);  tv1 = dpp_add<0x112>(tv1);
        tv0 = dpp_add<0x114>(tv0);  tv1 = dpp_add<0x114>(tv1);
        tv0 = dpp_add<0x118>(tv0);  tv1 = dpp_add<0x118>(tv1);
        if (sub == 15) {
            t2hS[uab]      = tv0;
            t2hS[uab + 32] = tv1;
        }

        bar_lds();  // 1: t2hS + t2iS[(t+1)&1] ready

        // ---- CD + cell ----
        // ih chains run on registers (tiR) while the th4 reads are in
        // flight; th chains join afterward.
        v2f aH0 = (v2f){bias0, 0.f}, aL0 = (v2f){0.f, 0.f};
        v2f aH1 = (v2f){bias1, 0.f}, aL1 = (v2f){0.f, 0.f};
        float4 thR[4];
#pragma unroll
        for (int qq = 0; qq < 4; ++qq) thR[qq] = th4[g * 4 + qq];  // in flight
#pragma unroll
        for (int qq = 0; qq < 4; ++qq) {
            v2f ixy = (v2f){tiR[qq].x, tiR[qq].y};
            v2f izw = (v2f){tiR[qq].z, tiR[qq].w};
            aH0 = pk_fma(ixy, c2ip0[2 * qq + 0], aH0);
            aL0 = pk_fma(izw, c2ip0[2 * qq + 1], aL0);
            aH1 = pk_fma(ixy, c2ip1[2 * qq + 0], aH1);
            aL1 = pk_fma(izw, c2ip1[2 * qq + 1], aL1);
        }
#pragma unroll
        for (int qq = 0; qq < 4; ++qq) {
            v2f txy = (v2f){thR[qq].x, thR[qq].y};
            v2f tzw = (v2f){thR[qq].z, thR[qq].w};
            aH0 = pk_fma(txy, c2hp0[2 * qq + 0], aH0);
            aL0 = pk_fma(tzw, c2hp0[2 * qq + 1], aL0);
            aH1 = pk_fma(txy, c2hp1[2 * qq + 0], aH1);
            aL1 = pk_fma(tzw, c2hp1[2 * qq + 1], aL1);
        }
        float acc0 = (aH0.x + aH0.y) + (aL0.x + aL0.y);
        float acc1 = (aH1.x + aH1.y) + (aL1.x + aL1.y);
        // unified activation: sigmoid(x)=1-1/(1+e^x), tanh(x)=1-2/(1+e^2x)
        float e0   = __builtin_amdgcn_exp2f(as * acc0);
        float e1   = __builtin_amdgcn_exp2f(as * acc1);
        float act0 = 1.0f - am * __builtin_amdgcn_rcpf(1.0f + e0);
        float act1 = 1.0f - am * __builtin_amdgcn_rcpf(1.0f + e1);
        // gather i,f,g,o within the quad via DPP broadcasts (serves both j)
        float gi0 = dpp_bcast<0x00>(act0), gi1 = dpp_bcast<0x00>(act1);
        float gf0 = dpp_bcast<0x55>(act0), gf1 = dpp_bcast<0x55>(act1);
        float gg0 = dpp_bcast<0xAA>(act0), gg1 = dpp_bcast<0xAA>(act1);
        float go0 = dpp_bcast<0xFF>(act0), go1 = dpp_bcast<0xFF>(act1);
        c0 = gf0 * c0 + gi0 * gg0;
        c1 = gf1 * c1 + gi1 * gg1;
        float ex0 = __builtin_amdgcn_exp2f(2.885390081777926f * c0);
        float ex1 = __builtin_amdgcn_exp2f(2.885390081777926f * c1);
        float th0 = 1.0f - 2.0f * __builtin_amdgcn_rcpf(1.0f + ex0);
        float th1 = 1.0f - 2.0f * __builtin_amdgcn_rcpf(1.0f + ex1);
        float h0 = go0 * th0;
        float h1 = go1 * th1;
        h0l = h0; h1l = h1;
        if (g == 0) {
            hS[hw0] = h0;                               // 4-way write, ~free
            hS[hw1] = h1;
            outB[t * 256 + j0] = h0;                    // never drained
            outB[t * 256 + j1] = h1;
        }

        bar_lds();  // 2: hS ready for next AB
    };

    for (int t = 0; t < 1024; t += 2) {
        body(t, preA, preB);
        body(t + 1, preB, preA);
    }

    if (g == 0) {
        out[16777216 + b * 256 + j0] = h0l;
        out[16777216 + b * 256 + j1] = h1l;
        out[16777216 + 16384 + b * 256 + j0] = c0;
        out[16777216 + 16384 + b * 256 + j1] = c1;
    }
}

extern "C" void kernel_launch(void* const* d_in, const int* in_sizes, int n_in,
                              void* d_out, int out_size, void* d_ws, size_t ws_size,
                              hipStream_t stream) {
    const float* x     = (const float*)d_in[0];
    const float* ih_g0 = (const float*)d_in[1];
    const float* ih_g1 = (const float*)d_in[2];
    const float* ih_g2 = (const float*)d_in[3];
    const float* ih_g3 = (const float*)d_in[4];
    const float* ih_b  = (const float*)d_in[5];
    const float* hh_g0 = (const float*)d_in[6];
    const float* hh_g1 = (const float*)d_in[7];
    const float* hh_g2 = (const float*)d_in[8];
    const float* hh_g3 = (const float*)d_in[9];
    const float* hh_b  = (const float*)d_in[10];
    float* out = (float*)d_out;
    float* ws  = (float*)d_ws;

    k_compose<<<132, 256, 0, stream>>>(ih_g0, ih_g1, ih_g2, ih_g3, ih_b,
                                       hh_g0, hh_g1, hh_g2, hh_g3, hh_b, ws);
    k_t2ih<<<1024, 256, 0, stream>>>(x, ws, ws + WS_T2);
    k_lstm<<<64, 512, 0, stream>>>(ws, ws + WS_T2, out);
}

// Round 6
// 879.301 us; speedup vs baseline: 1.0105x; 1.0105x over previous
//
#include <hip/hip_runtime.h>

// TT-LSTM: B=64, T=1024, D=H=256, F=16, R=16, NG=4.
// ws layout (floats):
//   A1ihT [64][256]  @ 0       ([g*16+s][m*16+n], composed g0*g1 for ih)
//   A1hT  [64][256]  @ 16384   (same for hh)
//   C2ih  [64][256]  @ 32768   ([g*16+s][o*16+p], composed g2*g3 for ih)
//   C2h   [64][256]  @ 49152
//   biasS [4][256]   @ 65536   (ih_bias + hh_bias)
//   T2ih  [65536][64]@ 66560   (first-stage ih contraction for all rows)

#define WS_A1I 0
#define WS_A1H 16384
#define WS_C2I 32768
#define WS_C2H 49152
#define WS_BIAS 65536
#define WS_T2 66560

typedef float v2f __attribute__((ext_vector_type(2)));

// Packed fp32 FMA: 2 FMAs/instruction.
__device__ __forceinline__ v2f pk_fma(v2f a, v2f b, v2f c) {
    v2f d;
    asm("v_pk_fma_f32 %0, %1, %2, %3" : "=v"(d) : "v"(a), "v"(b), "v"(c));
    return d;
}

// Barrier draining LDS only (lgkmcnt), NOT global loads/stores (vmcnt).
__device__ __forceinline__ void bar_lds() {
    asm volatile("s_waitcnt lgkmcnt(0)\n\ts_barrier" ::: "memory");
}

// DPP helpers: cross-lane at VALU rate (no DS pipe).
// row_shr:n = 0x110|n ; quad_perm(k,k,k,k) = k*0x55. bound_ctrl=1 -> 0 fill.
template <int CTRL>
__device__ __forceinline__ float dpp_add(float v) {
    int s = __builtin_amdgcn_update_dpp(0, __float_as_int(v), CTRL, 0xF, 0xF, true);
    return v + __int_as_float(s);
}
template <int CTRL>
__device__ __forceinline__ float dpp_bcast(float v) {
    int s = __builtin_amdgcn_update_dpp(0, __float_as_int(v), CTRL, 0xF, 0xF, true);
    return __int_as_float(s);
}

// ---------------- K0: compose TT cores ----------------
__global__ void k_compose(const float* __restrict__ g0i, const float* __restrict__ g1i,
                          const float* __restrict__ g2i, const float* __restrict__ g3i,
                          const float* __restrict__ bi,
                          const float* __restrict__ g0h, const float* __restrict__ g1h,
                          const float* __restrict__ g2h, const float* __restrict__ g3h,
                          const float* __restrict__ bh,
                          float* __restrict__ ws) {
    int id = blockIdx.x * 256 + threadIdx.x;
    if (id < 16384) {
        int g = id >> 12, s = (id >> 8) & 15, mn = id & 255;
        int m = mn >> 4, n = mn & 15;
        float aI = 0.f, aH = 0.f;
        for (int r = 0; r < 16; ++r) {
            aI += g0i[(g * 16 + m) * 16 + r] * g1i[((g * 16 + r) * 16 + n) * 16 + s];
            aH += g0h[(g * 16 + m) * 16 + r] * g1h[((g * 16 + r) * 16 + n) * 16 + s];
        }
        ws[WS_A1I + (g * 16 + s) * 256 + mn] = aI;
        ws[WS_A1H + (g * 16 + s) * 256 + mn] = aH;
    } else if (id < 32768) {
        int id2 = id - 16384;
        int g = id2 >> 12, s = (id2 >> 8) & 15, j = id2 & 255;
        int o = j >> 4, p = j & 15;
        float aI = 0.f, aH = 0.f;
        for (int t = 0; t < 16; ++t) {
            aI += g2i[((g * 16 + s) * 16 + o) * 16 + t] * g3i[(g * 16 + t) * 16 + p];
            aH += g2h[((g * 16 + s) * 16 + o) * 16 + t] * g3h[(g * 16 + t) * 16 + p];
        }
        ws[WS_C2I + (g * 16 + s) * 256 + j] = aI;
        ws[WS_C2H + (g * 16 + s) * 256 + j] = aH;
    } else if (id < 33792) {
        int id2 = id - 32768;
        ws[WS_BIAS + id2] = bi[id2] + bh[id2];
    }
}

// ---------------- K1: T2ih = X @ A1ih ----------------
// v6 rewrite. The r1 structure (4x4 tile, 8 reads/32pk, 1024 blocks over
// 2 generations) measured ~100-120us vs ~10us issue / ~40us DS floors;
// 4 micro-variants failed to move it. New structure:
//  - 256 blocks x 256 thr = exactly 1 block/CU, one generation, no tail.
//  - thread (rg=tid>>3, ug=tid&7) owns an 8-row x 8-u register tile:
//    16 LDS reads per 128 pk_fma (2x better DS/FLOP than r1).
//  - A (64KB) staged ONCE; X (256 rows x 32-K chunk) double-buffered with
//    reg-prefetch one chunk ahead; ONE __syncthreads per chunk.
//  - float4-slot XOR swizzle ((k4 + row>>3)&7 / (k4 + u>>3)&7): compute
//    reads are 8 distinct addrs x 8-lane broadcast on 8 distinct bank
//    quads -> conflict-free; staging writes are bank-balanced.
__global__ __launch_bounds__(256, 1) void k_t2ih(const float* __restrict__ x,
                                                 const float* __restrict__ ws,
                                                 float* __restrict__ T2) {
    __shared__ __align__(16) float4 As4[64 * 64];        // 64KB, swizzled
    __shared__ __align__(16) float4 Xs4[2][256 * 8];     // 64KB, swizzled
    const int tid = threadIdx.x;
    const long r0 = (long)blockIdx.x * 256;
    const int rg = tid >> 3;                             // 0..31: rows rg*8..+7
    const int ug = tid & 7;                              // 0..7 : u ug*8..+7

    const float4* X4g = (const float4*)x;                // row stride 64 f4
    const float4* A4  = (const float4*)(ws + WS_A1I);    // [64 u][64 f4]

    // ---- stage A once (swizzled) ----
#pragma unroll
    for (int it = 0; it < 16; ++it) {
        int idx = it * 256 + tid;                        // 0..4095
        int u = idx >> 6, k4 = idx & 63;
        As4[u * 64 + (k4 & ~7) + ((k4 + (u >> 3)) & 7)] = A4[idx];
    }
    // ---- stage X chunk 0 ----
#pragma unroll
    for (int it = 0; it < 8; ++it) {
        int idx = it * 256 + tid;                        // 0..2047
        int row = idx >> 3, c4 = idx & 7;
        Xs4[0][row * 8 + ((c4 + (row >> 3)) & 7)] = X4g[(r0 + row) * 64 + c4];
    }
    __syncthreads();

    v2f acc[8][8];
#pragma unroll
    for (int i = 0; i < 8; ++i)
#pragma unroll
        for (int uu = 0; uu < 8; ++uu) acc[i][uu] = (v2f){0.f, 0.f};

    float4 xr[8];
    for (int kc = 0; kc < 8; ++kc) {
        // prefetch next X chunk to registers (lands during compute)
        if (kc + 1 < 8) {
#pragma unroll
            for (int it = 0; it < 8; ++it) {
                int idx = it * 256 + tid;
                int row = idx >> 3, c4 = idx & 7;
                xr[it] = X4g[(r0 + row) * 64 + (kc + 1) * 8 + c4];
            }
        }
        const float4* Xb = Xs4[kc & 1];
#pragma unroll
        for (int k4 = 0; k4 < 8; ++k4) {
            float4 xv[8], av[8];
#pragma unroll
            for (int i = 0; i < 8; ++i)
                xv[i] = Xb[(rg * 8 + i) * 8 + ((k4 + rg) & 7)];
#pragma unroll
            for (int uu = 0; uu < 8; ++uu)
                av[uu] = As4[(ug * 8 + uu) * 64 + kc * 8 + ((k4 + ug) & 7)];
#pragma unroll
            for (int i = 0; i < 8; ++i)
#pragma unroll
                for (int uu = 0; uu < 8; ++uu) {
                    acc[i][uu] = pk_fma((v2f){xv[i].x, xv[i].y},
                                        (v2f){av[uu].x, av[uu].y}, acc[i][uu]);
                    acc[i][uu] = pk_fma((v2f){xv[i].z, xv[i].w},
                                        (v2f){av[uu].z, av[uu].w}, acc[i][uu]);
                }
        }
        if (kc + 1 < 8) {
#pragma unroll
            for (int it = 0; it < 8; ++it) {
                int idx = it * 256 + tid;
                int row = idx >> 3, c4 = idx & 7;
                Xs4[(kc + 1) & 1][row * 8 + ((c4 + (row >> 3)) & 7)] = xr[it];
            }
            __syncthreads();
        }
    }

    // ---- output: thread's u-range is 2 contiguous float4 per row ----
    float4* T24 = (float4*)T2;
#pragma unroll
    for (int i = 0; i < 8; ++i) {
        long row = r0 + rg * 8 + i;
#pragma unroll
        for (int s = 0; s < 2; ++s) {
            float4 o;
            o.x = acc[i][4 * s + 0].x + acc[i][4 * s + 0].y;
            o.y = acc[i][4 * s + 1].x + acc[i][4 * s + 1].y;
            o.z = acc[i][4 * s + 2].x + acc[i][4 * s + 2].y;
            o.w = acc[i][4 * s + 3].x + acc[i][4 * s + 3].y;
            T24[row * 16 + ug * 2 + s] = o;
        }
    }
}

// ---------------- K2: recurrent LSTM ----------------
// r4 structure verbatim (723us, best known): 64 blocks x 512 threads
// (8 waves, 2/SIMD), 2 outputs per thread, 2 barriers/step, DPP-only
// cross-lane. r5's ti4-hoist regressed (731) - th4 latency was already
// hidden by co-wave interleave; hoist only added AB-phase pressure.
// hS transposed layout: h[j] at word 64*((j&15)>>2)+4*(j>>4)+(j&3)
// -> AB reads hS4[kk*16+sub] bank-base 4*sub mod 32 = true 2-way (free).
__global__ __launch_bounds__(512, 2) void k_lstm(const float* __restrict__ ws,
                                                 const float* __restrict__ T2,
                                                 float* __restrict__ out) {
    __shared__ __align__(16) float hS[256];
    __shared__ __align__(16) float t2hS[64];
    __shared__ __align__(16) float t2iS[2][64];

    const int tid  = threadIdx.x;
    const int w    = tid >> 6;                          // 0..7
    const int lane = tid & 63;
    const int b    = blockIdx.x;

    // ---- AB weights: rows u0 and u1 = u0+32 of A1h, cols sub*16..+15 ----
    const int uab = 4 * w + (lane >> 4);                // 0..31
    const int sub = lane & 15;
    v2f a1p0[8], a1p1[8];
    {
        const float4* A1h4 = (const float4*)(ws + WS_A1H);
#pragma unroll
        for (int kk = 0; kk < 4; ++kk) {
            float4 v0 = A1h4[uab * 64 + sub * 4 + kk];
            float4 v1 = A1h4[(uab + 32) * 64 + sub * 4 + kk];
            a1p0[2 * kk + 0] = (v2f){v0.x, v0.y};
            a1p0[2 * kk + 1] = (v2f){v0.z, v0.w};
            a1p1[2 * kk + 0] = (v2f){v1.x, v1.y};
            a1p1[2 * kk + 1] = (v2f){v1.z, v1.w};
        }
    }

    // ---- CD weights: g=lane&3, jj=lane>>2, j0=16w+jj, j1=j0+128 ----
    const int jj = lane >> 2;                           // 0..15
    const int g  = lane & 3;
    const int j0 = 16 * w + jj;                         // 0..127
    const int j1 = j0 + 128;                            // 128..255
    v2f c2hp0[8], c2ip0[8], c2hp1[8], c2ip1[8];
#pragma unroll
    for (int qq = 0; qq < 4; ++qq) {
#pragma unroll
        for (int hh = 0; hh < 2; ++hh) {
            int s0 = 16 * g + 4 * qq + 2 * hh;
            c2hp0[2 * qq + hh] = (v2f){ws[WS_C2H + (s0 + 0) * 256 + j0],
                                       ws[WS_C2H + (s0 + 1) * 256 + j0]};
            c2ip0[2 * qq + hh] = (v2f){ws[WS_C2I + (s0 + 0) * 256 + j0],
                                       ws[WS_C2I + (s0 + 1) * 256 + j0]};
            c2hp1[2 * qq + hh] = (v2f){ws[WS_C2H + (s0 + 0) * 256 + j1],
                                       ws[WS_C2H + (s0 + 1) * 256 + j1]};
            c2ip1[2 * qq + hh] = (v2f){ws[WS_C2I + (s0 + 0) * 256 + j1],
                                       ws[WS_C2I + (s0 + 1) * 256 + j1]};
        }
    }
    float bias0 = ws[WS_BIAS + g * 256 + j0];
    float bias1 = ws[WS_BIAS + g * 256 + j1];
    const float am = (g == 2) ? 2.0f : 1.0f;            // tanh vs sigmoid
    const float as = 1.442695040888963f * am;

#pragma unroll
    for (int i = 0; i < 8; ++i)
        asm volatile("" : "+v"(a1p0[i]), "+v"(a1p1[i]), "+v"(c2hp0[i]),
                         "+v"(c2ip0[i]), "+v"(c2hp1[i]), "+v"(c2ip1[i]));

    // transposed hS slots: h[j] at word 64*((j&15)>>2) + 4*(j>>4) + (j&3)
    const int hw0 = ((jj >> 2) << 6) + 4 * w + (jj & 3);
    const int hw1 = hw0 + 32;                           // j1: j>>4 = w+8

    float c0 = 0.f, c1 = 0.f, h0l = 0.f, h1l = 0.f;
    if (tid < 256) hS[tid] = 0.f;
    const float* T2b = T2 + (long)b * 1024 * 64;
    const float4* T2b4 = (const float4*)T2b;
    float4 preA = make_float4(0.f, 0.f, 0.f, 0.f);
    float4 preB = make_float4(0.f, 0.f, 0.f, 0.f);
    if (tid < 16) {
        ((float4*)t2iS[0])[tid] = T2b4[tid];
        preA = T2b4[16 + tid];                          // T2[t=1]
    }
    bar_lds();

    float* outB = out + (long)b * 1024 * 256;
    const float4* hS4 = (const float4*)hS;
    const float4* th4 = (const float4*)t2hS;

    auto body = [&](int t, float4& preW, float4& preL) {
        // ---- AB (packed, 2 u-rows) ----
        v2f sA0 = (v2f){0.f, 0.f}, sB0 = (v2f){0.f, 0.f};
        v2f sA1 = (v2f){0.f, 0.f}, sB1 = (v2f){0.f, 0.f};
#pragma unroll
        for (int kk = 0; kk < 4; ++kk) {
            float4 hv = hS4[kk * 16 + sub];             // 2-way bcast, free
            v2f hxy = (v2f){hv.x, hv.y}, hzw = (v2f){hv.z, hv.w};
            sA0 = pk_fma(hxy, a1p0[2 * kk + 0], sA0);
            sB0 = pk_fma(hzw, a1p0[2 * kk + 1], sB0);
            sA1 = pk_fma(hxy, a1p1[2 * kk + 0], sA1);
            sB1 = pk_fma(hzw, a1p1[2 * kk + 1], sB1);
        }
        float tv0 = (sA0.x + sA0.y) + (sB0.x + sB0.y);
        float tv1 = (sA1.x + sA1.y) + (sB1.x + sB1.y);
        // stage next t2i + prefetch (independent; overlaps DPP chains)
        if ((tid < 16) && (t + 1 < 1024))
            ((float4*)t2iS[(t + 1) & 1])[tid] = preW;
        if ((tid < 16) && (t + 2 < 1024))
            preL = T2b4[(t + 2) * 16 + tid];
        // two interleaved DPP sums over the 16-lane row -> totals in sub==15
        tv0 = dpp_add<0x111>(tv0);  tv1 = dpp_add<0x111>(tv1);
        tv0 = dpp_add<0x112>(tv0);  tv1 = dpp_add<0x112>(tv1);
        tv0 = dpp_add<0x114>(tv0);  tv1 = dpp_add<0x114>(tv1);
        tv0 = dpp_add<0x118>(tv0);  tv1 = dpp_add<0x118>(tv1);
        if (sub == 15) {
            t2hS[uab]      = tv0;
            t2hS[uab + 32] = tv1;
        }

        bar_lds();  // 1: t2hS + t2iS[(t+1)&1] ready

        // ---- CD + cell: shared th/ti reads feed both j0 and j1 ----
        const float4* ti4 = (const float4*)t2iS[t & 1];
        v2f aH0 = (v2f){bias0, 0.f}, aL0 = (v2f){0.f, 0.f};
        v2f aH1 = (v2f){bias1, 0.f}, aL1 = (v2f){0.f, 0.f};
#pragma unroll
        for (int qq = 0; qq < 4; ++qq) {
            float4 th = th4[g * 4 + qq];                // 2-way bcast, free
            float4 ti = ti4[g * 4 + qq];
            v2f txy = (v2f){th.x, th.y}, tzw = (v2f){th.z, th.w};
            v2f ixy = (v2f){ti.x, ti.y}, izw = (v2f){ti.z, ti.w};
            aH0 = pk_fma(txy, c2hp0[2 * qq + 0], aH0);
            aL0 = pk_fma(tzw, c2hp0[2 * qq + 1], aL0);
            aH1 = pk_fma(txy, c2hp1[2 * qq + 0], aH1);
            aL1 = pk_fma(tzw, c2hp1[2 * qq + 1], aL1);
            aH0 = pk_fma(ixy, c2ip0[2 * qq + 0], aH0);
            aL0 = pk_fma(izw, c2ip0[2 * qq + 1], aL0);
            aH1 = pk_fma(ixy, c2ip1[2 * qq + 0], aH1);
            aL1 = pk_fma(izw, c2ip1[2 * qq + 1], aL1);
        }
        float acc0 = (aH0.x + aH0.y) + (aL0.x + aL0.y);
        float acc1 = (aH1.x + aH1.y) + (aL1.x + aL1.y);
        // unified activation: sigmoid(x)=1-1/(1+e^x), tanh(x)=1-2/(1+e^2x)
        float e0   = __builtin_amdgcn_exp2f(as * acc0);
        float e1   = __builtin_amdgcn_exp2f(as * acc1);
        float act0 = 1.0f - am * __builtin_amdgcn_rcpf(1.0f + e0);
        float act1 = 1.0f - am * __builtin_amdgcn_rcpf(1.0f + e1);
        // gather i,f,g,o within the quad via DPP broadcasts (serves both j)
        float gi0 = dpp_bcast<0x00>(act0), gi1 = dpp_bcast<0x00>(act1);
        float gf0 = dpp_bcast<0x55>(act0), gf1 = dpp_bcast<0x55>(act1);
        float gg0 = dpp_bcast<0xAA>(act0), gg1 = dpp_bcast<0xAA>(act1);
        float go0 = dpp_bcast<0xFF>(act0), go1 = dpp_bcast<0xFF>(act1);
        c0 = gf0 * c0 + gi0 * gg0;
        c1 = gf1 * c1 + gi1 * gg1;
        float ex0 = __builtin_amdgcn_exp2f(2.885390081777926f * c0);
        float ex1 = __builtin_amdgcn_exp2f(2.885390081777926f * c1);
        float th0 = 1.0f - 2.0f * __builtin_amdgcn_rcpf(1.0f + ex0);
        float th1 = 1.0f - 2.0f * __builtin_amdgcn_rcpf(1.0f + ex1);
        float h0 = go0 * th0;
        float h1 = go1 * th1;
        h0l = h0; h1l = h1;
        if (g == 0) {
            hS[hw0] = h0;                               // 4-way write, ~free
            hS[hw1] = h1;
            outB[t * 256 + j0] = h0;                    // never drained
            outB[t * 256 + j1] = h1;
        }

        bar_lds();  // 2: hS ready for next AB
    };

    for (int t = 0; t < 1024; t += 2) {
        body(t, preA, preB);
        body(t + 1, preB, preA);
    }

    if (g == 0) {
        out[16777216 + b * 256 + j0] = h0l;
        out[16777216 + b * 256 + j1] = h1l;
        out[16777216 + 16384 + b * 256 + j0] = c0;
        out[16777216 + 16384 + b * 256 + j1] = c1;
    }
}

extern "C" void kernel_launch(void* const* d_in, const int* in_sizes, int n_in,
                              void* d_out, int out_size, void* d_ws, size_t ws_size,
                              hipStream_t stream) {
    const float* x     = (const float*)d_in[0];
    const float* ih_g0 = (const float*)d_in[1];
    const float* ih_g1 = (const float*)d_in[2];
    const float* ih_g2 = (const float*)d_in[3];
    const float* ih_g3 = (const float*)d_in[4];
    const float* ih_b  = (const float*)d_in[5];
    const float* hh_g0 = (const float*)d_in[6];
    const float* hh_g1 = (const float*)d_in[7];
    const float* hh_g2 = (const float*)d_in[8];
    const float* hh_g3 = (const float*)d_in[9];
    const float* hh_b  = (const float*)d_in[10];
    float* out = (float*)d_out;
    float* ws  = (float*)d_ws;

    k_compose<<<132, 256, 0, stream>>>(ih_g0, ih_g1, ih_g2, ih_g3, ih_b,
                                       hh_g0, hh_g1, hh_g2, hh_g3, hh_b, ws);
    k_t2ih<<<256, 256, 0, stream>>>(x, ws, ws + WS_T2);
    k_lstm<<<64, 512, 0, stream>>>(ws, ws + WS_T2, out);
}